// Round 5
// baseline (47.959 us; speedup 1.0000x reference)
//
#include <hip/hip_runtime.h>
#include <stdint.h>

// ---------------------------------------------------------------------------
// Algebraic simplification of the reference:
//   * grad / softmax / top_k results are never used (dead code).
//   * kv_sel is a broadcast -> attention softmax is uniform -> attn@v_sel = v.
//   * Net computation:
//       V = x @ W_qkv[:, 1024:1536]                      (8192x512 @ 512x512)
//       Z[bi, (pi&1)*8+hi, ni, (pi>>1)*64+d] = gelu(V[bi,pi,ni,hi*64+d])
//       Y = Z @ W_out + b_out                            (8192x512 @ 512x512)
//   with b=2, p=16, n=256, h=8, dh=64, M = b*p*n = 8192, K = N = 512.
//
// R3/R4: GEMM1 epilogue de-risked: inline rational erf (no erff libcall; HW
// v_exp_f32 via __builtin_amdgcn_exp2f) and LINEAR Z store; the permutation
// is folded into GEMM2's A-tile source addressing (global_load_lds src is
// per-lane; 16B granules stay within one 64-col block -> pure address math).
// ---------------------------------------------------------------------------

typedef __bf16 bf16x8 __attribute__((ext_vector_type(8)));
typedef float f32x4 __attribute__((ext_vector_type(4)));
typedef unsigned short u16x8 __attribute__((ext_vector_type(8)));

#define HD __device__ __forceinline__

HD uint16_t f2bf(float f) {
  union { float f; uint32_t u; } v; v.f = f;
  uint32_t u = v.u;
  u += 0x7fffu + ((u >> 16) & 1u);   // RNE
  return (uint16_t)(u >> 16);
}

HD void gll16(const void* g, void* l) {
  __builtin_amdgcn_global_load_lds(
      (__attribute__((address_space(1))) void*)g,
      (__attribute__((address_space(3))) void*)l, 16, 0, 0);
}

// Exact-enough GELU: erf via Abramowitz-Stegun 7.1.25 (|err|<=2.5e-5),
// fully inline: v_rcp_f32 + v_exp_f32 (2^x) + ~10 FMAs. No libcalls.
HD float gelu(float v) {
  float x = v * 0.70710678118654752440f;
  float ax = __builtin_fabsf(x);
  float t = __builtin_amdgcn_rcpf(1.0f + 0.47047f * ax);
  float poly = t * (0.3480242f + t * (-0.0958798f + t * 0.7478556f));
  float e = 1.0f - poly * __builtin_amdgcn_exp2f(-ax * ax * 1.44269504088896340736f);
  // copysign(e, x)
  union { float f; uint32_t u; } ue, ux;
  ue.f = e; ux.f = x;
  ue.u = (ue.u & 0x7fffffffu) | (ux.u & 0x80000000u);
  return 0.5f * v * (1.0f + ue.f);
}

// ---------------------------------------------------------------------------
// X fp32 -> bf16 streaming convert. 8 elem/thread, 2048 blocks (exact cover).
// ---------------------------------------------------------------------------
__global__ __launch_bounds__(256) void k_cvtx(
    const float* __restrict__ X, uint16_t* __restrict__ Xb) {
  const size_t i = ((size_t)blockIdx.x * 256 + threadIdx.x) * 8;
  f32x4 a = *(const f32x4*)(X + i);
  f32x4 b = *(const f32x4*)(X + i + 4);
  u16x8 o;
  o[0] = f2bf(a[0]); o[1] = f2bf(a[1]); o[2] = f2bf(a[2]); o[3] = f2bf(a[3]);
  o[4] = f2bf(b[0]); o[5] = f2bf(b[1]); o[6] = f2bf(b[2]); o[7] = f2bf(b[3]);
  *(u16x8*)(Xb + i) = o;
}

// ---------------------------------------------------------------------------
// Both weight transposes (fp32 -> bf16, out[c][k] = in[k][coloff+c]) in one
// launch: blockIdx.z selects {W_qkv v-slice, W_out}. 64x64 tiles, 256 thr.
// ---------------------------------------------------------------------------
__global__ __launch_bounds__(256) void k_prep(
    const float* __restrict__ Wqkv, const float* __restrict__ Wout,
    uint16_t* __restrict__ WvT, uint16_t* __restrict__ WoT) {
  const float* in;
  uint16_t* out;
  int ldin, coloff;
  if (blockIdx.z == 0) { in = Wqkv; ldin = 1536; coloff = 1024; out = WvT; }
  else                 { in = Wout; ldin = 512;  coloff = 0;    out = WoT; }

  __shared__ uint16_t t[64][66];
  const int tid = threadIdx.x;
  const int tx = tid & 63;
  const int ty = tid >> 6;
  const int j0 = blockIdx.x * 64;
  const int k0 = blockIdx.y * 64;
#pragma unroll
  for (int r = 0; r < 16; ++r) {
    int k = ty * 16 + r;
    t[k][tx] = f2bf(in[(size_t)(k0 + k) * ldin + coloff + j0 + tx]);
  }
  __syncthreads();
#pragma unroll
  for (int r = 0; r < 16; ++r) {
    int j = ty * 16 + r;
    out[(size_t)(j0 + j) * 512 + k0 + tx] = t[tx][j];
  }
}

// ---------------------------------------------------------------------------
// GEMM1: Zlin = gelu(Xb @ Wv), LINEAR bf16 store (no permute, no libcall).
// BM=64 BN=128 BK=32, 256 thr (4 waves, each 32x64 = 2x4 frags of 16x16).
// ---------------------------------------------------------------------------
__global__ __launch_bounds__(256) void k_gemm1(
    const uint16_t* __restrict__ Xb,   // [8192][512] bf16 (just written)
    const uint16_t* __restrict__ WT,   // [512][512] bf16, WT[col][k]
    uint16_t* __restrict__ Zlin) {     // [8192][512] bf16, LINEAR
  __shared__ __align__(16) uint16_t As[2][4][64][8];
  __shared__ __align__(16) uint16_t Bs[2][4][128][8];

  const int tid = threadIdx.x;
  const int lane = tid & 63;
  const int wid = tid >> 6;
  const int wm = wid >> 1;
  const int wn = wid & 1;
  const int tm = blockIdx.y * 64;
  const int tn = blockIdx.x * 128;

  f32x4 acc[2][4];
  const f32x4 zero = {0.f, 0.f, 0.f, 0.f};
#pragma unroll
  for (int i = 0; i < 2; ++i)
#pragma unroll
    for (int j = 0; j < 4; ++j) acc[i][j] = zero;

  auto stage = [&](int kk, int buf) {
    gll16(Xb + (size_t)(tm + lane) * 512 + kk * 32 + wid * 8,
          &As[buf][wid][0][0]);
#pragma unroll
    for (int s = 0; s < 2; ++s) {
      int t = wid + 4 * s;
      int kc = t >> 1;
      int cb = (t & 1) * 64;
      gll16(WT + (size_t)(tn + cb + lane) * 512 + kk * 32 + kc * 8,
            &Bs[buf][kc][cb][0]);
    }
  };

  stage(0, 0);
  __syncthreads();

  const int lr = lane & 15;
  const int lk = lane >> 4;

#pragma unroll 2
  for (int kk = 0; kk < 16; ++kk) {
    const int cur = kk & 1;
    if (kk + 1 < 16) stage(kk + 1, cur ^ 1);
    bf16x8 a[2], b[4];
#pragma unroll
    for (int mi = 0; mi < 2; ++mi)
      a[mi] = *(const bf16x8*)&As[cur][lk][wm * 32 + mi * 16 + lr][0];
#pragma unroll
    for (int nj = 0; nj < 4; ++nj)
      b[nj] = *(const bf16x8*)&Bs[cur][lk][wn * 64 + nj * 16 + lr][0];
#pragma unroll
    for (int mi = 0; mi < 2; ++mi)
#pragma unroll
      for (int nj = 0; nj < 4; ++nj)
        acc[mi][nj] = __builtin_amdgcn_mfma_f32_16x16x32_bf16(
            a[mi], b[nj], acc[mi][nj], 0, 0, 0);
    __syncthreads();
  }

  // Epilogue: inline gelu + linear bf16 store.
#pragma unroll
  for (int mi = 0; mi < 2; ++mi)
#pragma unroll
    for (int nj = 0; nj < 4; ++nj)
#pragma unroll
      for (int r = 0; r < 4; ++r) {
        int m = tm + wm * 32 + mi * 16 + lk * 4 + r;
        int j = tn + wn * 64 + nj * 16 + lr;
        Zlin[(size_t)m * 512 + j] = f2bf(gelu(acc[mi][nj][r]));
      }
}

// ---------------------------------------------------------------------------
// GEMM2: Y = Z @ Wout + bias, fp32 out. The reference's permutation is folded
// into the A-tile SOURCE addressing:
//   A[m2][k2] = Zlin[m][j],  m2=(bi,pp,ni), k2=(q,di):
//     pi = 2q + (pp>>3), hi = pp&7, m = bi*4096+pi*256+ni, j = hi*64+di.
// Each 16B granule (8 consecutive k2, 8-aligned) stays within one q/64-block,
// so row m and column base are constant per granule.
// ---------------------------------------------------------------------------
__global__ __launch_bounds__(256) void k_gemm_bias(
    const uint16_t* __restrict__ Zlin, // [8192][512] bf16, linear V-gelu
    const uint16_t* __restrict__ WT,   // [512][512] bf16, WoT[col][k]
    const float* __restrict__ bias,    // [512]
    float* __restrict__ Y) {           // [8192][512] fp32
  __shared__ __align__(16) uint16_t As[2][4][64][8];
  __shared__ __align__(16) uint16_t Bs[2][4][128][8];

  const int tid = threadIdx.x;
  const int lane = tid & 63;
  const int wid = tid >> 6;
  const int wm = wid >> 1;
  const int wn = wid & 1;
  const int tm = blockIdx.y * 64;
  const int tn = blockIdx.x * 128;

  f32x4 acc[2][4];
  const f32x4 zero = {0.f, 0.f, 0.f, 0.f};
#pragma unroll
  for (int i = 0; i < 2; ++i)
#pragma unroll
    for (int j = 0; j < 4; ++j) acc[i][j] = zero;

  // Permuted-source A row pieces (row m2 = tm + lane is fixed per thread).
  const int m2 = tm + lane;
  const int bi = m2 >> 12;
  const int pp = (m2 >> 8) & 15;
  const int ni = m2 & 255;
  const int mbase = bi * 4096 + (pp >> 3) * 256 + ni;  // + q*512 rows
  const int jbase = (pp & 7) * 64;

  auto stage = [&](int kk, int buf) {
    int k2 = kk * 32 + wid * 8;
    int q = k2 >> 6;
    int di = k2 & 63;
    gll16(Zlin + (size_t)(mbase + q * 512) * 512 + jbase + di,
          &As[buf][wid][0][0]);
#pragma unroll
    for (int s = 0; s < 2; ++s) {
      int t = wid + 4 * s;
      int kc = t >> 1;
      int cb = (t & 1) * 64;
      gll16(WT + (size_t)(tn + cb + lane) * 512 + kk * 32 + kc * 8,
            &Bs[buf][kc][cb][0]);
    }
  };

  stage(0, 0);
  __syncthreads();

  const int lr = lane & 15;
  const int lk = lane >> 4;

#pragma unroll 2
  for (int kk = 0; kk < 16; ++kk) {
    const int cur = kk & 1;
    if (kk + 1 < 16) stage(kk + 1, cur ^ 1);
    bf16x8 a[2], b[4];
#pragma unroll
    for (int mi = 0; mi < 2; ++mi)
      a[mi] = *(const bf16x8*)&As[cur][lk][wm * 32 + mi * 16 + lr][0];
#pragma unroll
    for (int nj = 0; nj < 4; ++nj)
      b[nj] = *(const bf16x8*)&Bs[cur][lk][wn * 64 + nj * 16 + lr][0];
#pragma unroll
    for (int mi = 0; mi < 2; ++mi)
#pragma unroll
      for (int nj = 0; nj < 4; ++nj)
        acc[mi][nj] = __builtin_amdgcn_mfma_f32_16x16x32_bf16(
            a[mi], b[nj], acc[mi][nj], 0, 0, 0);
    __syncthreads();
  }

#pragma unroll
  for (int mi = 0; mi < 2; ++mi)
#pragma unroll
    for (int nj = 0; nj < 4; ++nj) {
      int j = tn + wn * 64 + nj * 16 + lr;
      float bj = bias[j];
#pragma unroll
      for (int r = 0; r < 4; ++r) {
        int m = tm + wm * 32 + mi * 16 + lk * 4 + r;
        Y[(size_t)m * 512 + j] = acc[mi][nj][r] + bj;
      }
    }
}

// ---------------------------------------------------------------------------
extern "C" void kernel_launch(void* const* d_in, const int* in_sizes, int n_in,
                              void* d_out, int out_size, void* d_ws, size_t ws_size,
                              hipStream_t stream) {
  const float* x    = (const float*)d_in[0];
  // d_in[1] = grad : provably unused by the reference's dataflow.
  const float* Wqkv = (const float*)d_in[2];   // [512][1536]
  const float* Wout = (const float*)d_in[3];   // [512][512]
  const float* bout = (const float*)d_in[4];   // [512]
  float* Y = (float*)d_out;

  uint16_t* WvT = (uint16_t*)d_ws;             // 512*512 bf16 (0.5 MB)
  uint16_t* WoT = WvT + 512 * 512;             // 0.5 MB
  uint16_t* Z   = WoT + 512 * 512;             // 8192*512 bf16 (8 MB)
  // Xb parked in d_out: dead storage until GEMM2 overwrites it with Y.
  uint16_t* Xb  = (uint16_t*)d_out;            // 8192*512 bf16 (8 MB of 16 MB)

  dim3 tb(256);
  k_cvtx<<<dim3(2048), tb, 0, stream>>>(x, Xb);
  k_prep<<<dim3(8, 8, 2), tb, 0, stream>>>(Wqkv, Wout, WvT, WoT);
  k_gemm1<<<dim3(4, 128), tb, 0, stream>>>(Xb, WvT, Z);
  k_gemm_bias<<<dim3(4, 128), tb, 0, stream>>>(Z, WoT, bout, Y);
}

// Round 6
// 47.951 us; speedup vs baseline: 1.0002x; 1.0002x over previous
//
#include <hip/hip_runtime.h>
#include <stdint.h>

// ---------------------------------------------------------------------------
// Algebraic simplification of the reference:
//   * grad / softmax / top_k results are never used (dead code).
//   * kv_sel is a broadcast -> attention softmax is uniform -> attn@v_sel = v.
//   * Net computation:
//       V = x @ W_qkv[:, 1024:1536]                      (8192x512 @ 512x512)
//       Z[bi, (pi&1)*8+hi, ni, (pi>>1)*64+d] = gelu(V[bi,pi,ni,hi*64+d])
//       Y = Z @ W_out + b_out                            (8192x512 @ 512x512)
//   with b=2, p=16, n=256, h=8, dh=64, M = b*p*n = 8192, K = N = 512.
//
// R6: ONE change vs R5 — Xb moved from d_out into d_ws. Theory: d_out reads
// bypass L2/L3 (fine-grained alloc); R2-R5's gemm1 A-reads showed 0% cache
// hit (FETCH 33 MB for an 8-MB just-written array with 4x reuse) while the
// identical-structure gemm_bias reading d_ws-resident Z runs 15x faster.
// ---------------------------------------------------------------------------

typedef __bf16 bf16x8 __attribute__((ext_vector_type(8)));
typedef float f32x4 __attribute__((ext_vector_type(4)));
typedef unsigned short u16x8 __attribute__((ext_vector_type(8)));

#define HD __device__ __forceinline__

HD uint16_t f2bf(float f) {
  union { float f; uint32_t u; } v; v.f = f;
  uint32_t u = v.u;
  u += 0x7fffu + ((u >> 16) & 1u);   // RNE
  return (uint16_t)(u >> 16);
}

HD void gll16(const void* g, void* l) {
  __builtin_amdgcn_global_load_lds(
      (__attribute__((address_space(1))) void*)g,
      (__attribute__((address_space(3))) void*)l, 16, 0, 0);
}

// Exact-enough GELU: erf via Abramowitz-Stegun 7.1.25 (|err|<=2.5e-5),
// fully inline: v_rcp_f32 + v_exp_f32 (2^x) + ~10 FMAs. No libcalls.
HD float gelu(float v) {
  float x = v * 0.70710678118654752440f;
  float ax = __builtin_fabsf(x);
  float t = __builtin_amdgcn_rcpf(1.0f + 0.47047f * ax);
  float poly = t * (0.3480242f + t * (-0.0958798f + t * 0.7478556f));
  float e = 1.0f - poly * __builtin_amdgcn_exp2f(-ax * ax * 1.44269504088896340736f);
  // copysign(e, x)
  union { float f; uint32_t u; } ue, ux;
  ue.f = e; ux.f = x;
  ue.u = (ue.u & 0x7fffffffu) | (ux.u & 0x80000000u);
  return 0.5f * v * (1.0f + ue.f);
}

// ---------------------------------------------------------------------------
// X fp32 -> bf16 streaming convert. 8 elem/thread, 2048 blocks (exact cover).
// ---------------------------------------------------------------------------
__global__ __launch_bounds__(256) void k_cvtx(
    const float* __restrict__ X, uint16_t* __restrict__ Xb) {
  const size_t i = ((size_t)blockIdx.x * 256 + threadIdx.x) * 8;
  f32x4 a = *(const f32x4*)(X + i);
  f32x4 b = *(const f32x4*)(X + i + 4);
  u16x8 o;
  o[0] = f2bf(a[0]); o[1] = f2bf(a[1]); o[2] = f2bf(a[2]); o[3] = f2bf(a[3]);
  o[4] = f2bf(b[0]); o[5] = f2bf(b[1]); o[6] = f2bf(b[2]); o[7] = f2bf(b[3]);
  *(u16x8*)(Xb + i) = o;
}

// ---------------------------------------------------------------------------
// Both weight transposes (fp32 -> bf16, out[c][k] = in[k][coloff+c]) in one
// launch: blockIdx.z selects {W_qkv v-slice, W_out}. 64x64 tiles, 256 thr.
// ---------------------------------------------------------------------------
__global__ __launch_bounds__(256) void k_prep(
    const float* __restrict__ Wqkv, const float* __restrict__ Wout,
    uint16_t* __restrict__ WvT, uint16_t* __restrict__ WoT) {
  const float* in;
  uint16_t* out;
  int ldin, coloff;
  if (blockIdx.z == 0) { in = Wqkv; ldin = 1536; coloff = 1024; out = WvT; }
  else                 { in = Wout; ldin = 512;  coloff = 0;    out = WoT; }

  __shared__ uint16_t t[64][66];
  const int tid = threadIdx.x;
  const int tx = tid & 63;
  const int ty = tid >> 6;
  const int j0 = blockIdx.x * 64;
  const int k0 = blockIdx.y * 64;
#pragma unroll
  for (int r = 0; r < 16; ++r) {
    int k = ty * 16 + r;
    t[k][tx] = f2bf(in[(size_t)(k0 + k) * ldin + coloff + j0 + tx]);
  }
  __syncthreads();
#pragma unroll
  for (int r = 0; r < 16; ++r) {
    int j = ty * 16 + r;
    out[(size_t)(j0 + j) * 512 + k0 + tx] = t[tx][j];
  }
}

// ---------------------------------------------------------------------------
// GEMM1: Zlin = gelu(Xb @ Wv), LINEAR bf16 store (no permute, no libcall).
// BM=64 BN=128 BK=32, 256 thr (4 waves, each 32x64 = 2x4 frags of 16x16).
// ---------------------------------------------------------------------------
__global__ __launch_bounds__(256) void k_gemm1(
    const uint16_t* __restrict__ Xb,   // [8192][512] bf16 (just written, d_ws)
    const uint16_t* __restrict__ WT,   // [512][512] bf16, WT[col][k]
    uint16_t* __restrict__ Zlin) {     // [8192][512] bf16, LINEAR
  __shared__ __align__(16) uint16_t As[2][4][64][8];
  __shared__ __align__(16) uint16_t Bs[2][4][128][8];

  const int tid = threadIdx.x;
  const int lane = tid & 63;
  const int wid = tid >> 6;
  const int wm = wid >> 1;
  const int wn = wid & 1;
  const int tm = blockIdx.y * 64;
  const int tn = blockIdx.x * 128;

  f32x4 acc[2][4];
  const f32x4 zero = {0.f, 0.f, 0.f, 0.f};
#pragma unroll
  for (int i = 0; i < 2; ++i)
#pragma unroll
    for (int j = 0; j < 4; ++j) acc[i][j] = zero;

  auto stage = [&](int kk, int buf) {
    gll16(Xb + (size_t)(tm + lane) * 512 + kk * 32 + wid * 8,
          &As[buf][wid][0][0]);
#pragma unroll
    for (int s = 0; s < 2; ++s) {
      int t = wid + 4 * s;
      int kc = t >> 1;
      int cb = (t & 1) * 64;
      gll16(WT + (size_t)(tn + cb + lane) * 512 + kk * 32 + kc * 8,
            &Bs[buf][kc][cb][0]);
    }
  };

  stage(0, 0);
  __syncthreads();

  const int lr = lane & 15;
  const int lk = lane >> 4;

#pragma unroll 2
  for (int kk = 0; kk < 16; ++kk) {
    const int cur = kk & 1;
    if (kk + 1 < 16) stage(kk + 1, cur ^ 1);
    bf16x8 a[2], b[4];
#pragma unroll
    for (int mi = 0; mi < 2; ++mi)
      a[mi] = *(const bf16x8*)&As[cur][lk][wm * 32 + mi * 16 + lr][0];
#pragma unroll
    for (int nj = 0; nj < 4; ++nj)
      b[nj] = *(const bf16x8*)&Bs[cur][lk][wn * 64 + nj * 16 + lr][0];
#pragma unroll
    for (int mi = 0; mi < 2; ++mi)
#pragma unroll
      for (int nj = 0; nj < 4; ++nj)
        acc[mi][nj] = __builtin_amdgcn_mfma_f32_16x16x32_bf16(
            a[mi], b[nj], acc[mi][nj], 0, 0, 0);
    __syncthreads();
  }

  // Epilogue: inline gelu + linear bf16 store.
#pragma unroll
  for (int mi = 0; mi < 2; ++mi)
#pragma unroll
    for (int nj = 0; nj < 4; ++nj)
#pragma unroll
      for (int r = 0; r < 4; ++r) {
        int m = tm + wm * 32 + mi * 16 + lk * 4 + r;
        int j = tn + wn * 64 + nj * 16 + lr;
        Zlin[(size_t)m * 512 + j] = f2bf(gelu(acc[mi][nj][r]));
      }
}

// ---------------------------------------------------------------------------
// GEMM2: Y = Z @ Wout + bias, fp32 out. The reference's permutation is folded
// into the A-tile SOURCE addressing:
//   A[m2][k2] = Zlin[m][j],  m2=(bi,pp,ni), k2=(q,di):
//     pi = 2q + (pp>>3), hi = pp&7, m = bi*4096+pi*256+ni, j = hi*64+di.
// Each 16B granule (8 consecutive k2, 8-aligned) stays within one q/64-block,
// so row m and column base are constant per granule.
// ---------------------------------------------------------------------------
__global__ __launch_bounds__(256) void k_gemm_bias(
    const uint16_t* __restrict__ Zlin, // [8192][512] bf16, linear V-gelu
    const uint16_t* __restrict__ WT,   // [512][512] bf16, WoT[col][k]
    const float* __restrict__ bias,    // [512]
    float* __restrict__ Y) {           // [8192][512] fp32
  __shared__ __align__(16) uint16_t As[2][4][64][8];
  __shared__ __align__(16) uint16_t Bs[2][4][128][8];

  const int tid = threadIdx.x;
  const int lane = tid & 63;
  const int wid = tid >> 6;
  const int wm = wid >> 1;
  const int wn = wid & 1;
  const int tm = blockIdx.y * 64;
  const int tn = blockIdx.x * 128;

  f32x4 acc[2][4];
  const f32x4 zero = {0.f, 0.f, 0.f, 0.f};
#pragma unroll
  for (int i = 0; i < 2; ++i)
#pragma unroll
    for (int j = 0; j < 4; ++j) acc[i][j] = zero;

  // Permuted-source A row pieces (row m2 = tm + lane is fixed per thread).
  const int m2 = tm + lane;
  const int bi = m2 >> 12;
  const int pp = (m2 >> 8) & 15;
  const int ni = m2 & 255;
  const int mbase = bi * 4096 + (pp >> 3) * 256 + ni;  // + q*512 rows
  const int jbase = (pp & 7) * 64;

  auto stage = [&](int kk, int buf) {
    int k2 = kk * 32 + wid * 8;
    int q = k2 >> 6;
    int di = k2 & 63;
    gll16(Zlin + (size_t)(mbase + q * 512) * 512 + jbase + di,
          &As[buf][wid][0][0]);
#pragma unroll
    for (int s = 0; s < 2; ++s) {
      int t = wid + 4 * s;
      int kc = t >> 1;
      int cb = (t & 1) * 64;
      gll16(WT + (size_t)(tn + cb + lane) * 512 + kk * 32 + kc * 8,
            &Bs[buf][kc][cb][0]);
    }
  };

  stage(0, 0);
  __syncthreads();

  const int lr = lane & 15;
  const int lk = lane >> 4;

#pragma unroll 2
  for (int kk = 0; kk < 16; ++kk) {
    const int cur = kk & 1;
    if (kk + 1 < 16) stage(kk + 1, cur ^ 1);
    bf16x8 a[2], b[4];
#pragma unroll
    for (int mi = 0; mi < 2; ++mi)
      a[mi] = *(const bf16x8*)&As[cur][lk][wm * 32 + mi * 16 + lr][0];
#pragma unroll
    for (int nj = 0; nj < 4; ++nj)
      b[nj] = *(const bf16x8*)&Bs[cur][lk][wn * 64 + nj * 16 + lr][0];
#pragma unroll
    for (int mi = 0; mi < 2; ++mi)
#pragma unroll
      for (int nj = 0; nj < 4; ++nj)
        acc[mi][nj] = __builtin_amdgcn_mfma_f32_16x16x32_bf16(
            a[mi], b[nj], acc[mi][nj], 0, 0, 0);
    __syncthreads();
  }

#pragma unroll
  for (int mi = 0; mi < 2; ++mi)
#pragma unroll
    for (int nj = 0; nj < 4; ++nj) {
      int j = tn + wn * 64 + nj * 16 + lr;
      float bj = bias[j];
#pragma unroll
      for (int r = 0; r < 4; ++r) {
        int m = tm + wm * 32 + mi * 16 + lk * 4 + r;
        Y[(size_t)m * 512 + j] = acc[mi][nj][r] + bj;
      }
    }
}

// ---------------------------------------------------------------------------
extern "C" void kernel_launch(void* const* d_in, const int* in_sizes, int n_in,
                              void* d_out, int out_size, void* d_ws, size_t ws_size,
                              hipStream_t stream) {
  const float* x    = (const float*)d_in[0];
  // d_in[1] = grad : provably unused by the reference's dataflow.
  const float* Wqkv = (const float*)d_in[2];   // [512][1536]
  const float* Wout = (const float*)d_in[3];   // [512][512]
  const float* bout = (const float*)d_in[4];   // [512]
  float* Y = (float*)d_out;

  // ALL intermediates in d_ws (total 17 MB; ws is ~256 MiB per the harness
  // fill of 262144 KB). d_out is written exactly once, at the end.
  uint16_t* WvT = (uint16_t*)d_ws;             // 512*512 bf16 (0.5 MB)
  uint16_t* WoT = WvT + 512 * 512;             // 0.5 MB
  uint16_t* Z   = WoT + 512 * 512;             // 8192*512 bf16 (8 MB)
  uint16_t* Xb  = Z + 8192 * 512;              // 8192*512 bf16 (8 MB)

  dim3 tb(256);
  k_cvtx<<<dim3(2048), tb, 0, stream>>>(x, Xb);
  k_prep<<<dim3(8, 8, 2), tb, 0, stream>>>(Wqkv, Wout, WvT, WoT);
  k_gemm1<<<dim3(4, 128), tb, 0, stream>>>(Xb, WvT, Z);
  k_gemm_bias<<<dim3(4, 128), tb, 0, stream>>>(Z, WoT, bout, Y);
}

// Round 7
// 47.584 us; speedup vs baseline: 1.0079x; 1.0077x over previous
//
#include <hip/hip_runtime.h>
#include <stdint.h>

// ---------------------------------------------------------------------------
// Algebraic simplification of the reference:
//   * grad / softmax / top_k results are never used (dead code).
//   * kv_sel is a broadcast -> attention softmax is uniform -> attn@v_sel = v.
//   * Net computation:
//       V = x @ W_qkv[:, 1024:1536]                      (8192x512 @ 512x512)
//       Z[bi, (pi&1)*8+hi, ni, (pi>>1)*64+d] = gelu(V[bi,pi,ni,hi*64+d])
//       Y = Z @ W_out + b_out                            (8192x512 @ 512x512)
//   with b=2, p=16, n=256, h=8, dh=64, M = b*p*n = 8192, K = N = 512.
//
// R7: k_gemm1 gets a depth-4 pipeline (T3/T4): 4 LDS buffers, counted
// s_waitcnt vmcnt(6) (never 0 in-loop), raw s_barrier (NOT __syncthreads,
// which drains vmcnt). Theory: gemm1 executes while the harness's 268-MB
// ws-poison fill saturates HBM + evicts L3; per-iteration drain-to-0 made it
// eat ~3000-cyc queue-delayed latency 16x serially. Loads now span 3 iters.
// ---------------------------------------------------------------------------

typedef __bf16 bf16x8 __attribute__((ext_vector_type(8)));
typedef float f32x4 __attribute__((ext_vector_type(4)));
typedef unsigned short u16x8 __attribute__((ext_vector_type(8)));

#define HD __device__ __forceinline__

HD uint16_t f2bf(float f) {
  union { float f; uint32_t u; } v; v.f = f;
  uint32_t u = v.u;
  u += 0x7fffu + ((u >> 16) & 1u);   // RNE
  return (uint16_t)(u >> 16);
}

HD void gll16(const void* g, void* l) {
  __builtin_amdgcn_global_load_lds(
      (__attribute__((address_space(1))) void*)g,
      (__attribute__((address_space(3))) void*)l, 16, 0, 0);
}

// Exact-enough GELU: erf via Abramowitz-Stegun 7.1.25 (|err|<=2.5e-5).
HD float gelu(float v) {
  float x = v * 0.70710678118654752440f;
  float ax = __builtin_fabsf(x);
  float t = __builtin_amdgcn_rcpf(1.0f + 0.47047f * ax);
  float poly = t * (0.3480242f + t * (-0.0958798f + t * 0.7478556f));
  float e = 1.0f - poly * __builtin_amdgcn_exp2f(-ax * ax * 1.44269504088896340736f);
  union { float f; uint32_t u; } ue, ux;
  ue.f = e; ux.f = x;
  ue.u = (ue.u & 0x7fffffffu) | (ux.u & 0x80000000u);
  return 0.5f * v * (1.0f + ue.f);
}

// ---------------------------------------------------------------------------
// X fp32 -> bf16 streaming convert. 8 elem/thread, 2048 blocks (exact cover).
// ---------------------------------------------------------------------------
__global__ __launch_bounds__(256) void k_cvtx(
    const float* __restrict__ X, uint16_t* __restrict__ Xb) {
  const size_t i = ((size_t)blockIdx.x * 256 + threadIdx.x) * 8;
  f32x4 a = *(const f32x4*)(X + i);
  f32x4 b = *(const f32x4*)(X + i + 4);
  u16x8 o;
  o[0] = f2bf(a[0]); o[1] = f2bf(a[1]); o[2] = f2bf(a[2]); o[3] = f2bf(a[3]);
  o[4] = f2bf(b[0]); o[5] = f2bf(b[1]); o[6] = f2bf(b[2]); o[7] = f2bf(b[3]);
  *(u16x8*)(Xb + i) = o;
}

// ---------------------------------------------------------------------------
// Both weight transposes (fp32 -> bf16, out[c][k] = in[k][coloff+c]).
// ---------------------------------------------------------------------------
__global__ __launch_bounds__(256) void k_prep(
    const float* __restrict__ Wqkv, const float* __restrict__ Wout,
    uint16_t* __restrict__ WvT, uint16_t* __restrict__ WoT) {
  const float* in;
  uint16_t* out;
  int ldin, coloff;
  if (blockIdx.z == 0) { in = Wqkv; ldin = 1536; coloff = 1024; out = WvT; }
  else                 { in = Wout; ldin = 512;  coloff = 0;    out = WoT; }

  __shared__ uint16_t t[64][66];
  const int tid = threadIdx.x;
  const int tx = tid & 63;
  const int ty = tid >> 6;
  const int j0 = blockIdx.x * 64;
  const int k0 = blockIdx.y * 64;
#pragma unroll
  for (int r = 0; r < 16; ++r) {
    int k = ty * 16 + r;
    t[k][tx] = f2bf(in[(size_t)(k0 + k) * ldin + coloff + j0 + tx]);
  }
  __syncthreads();
#pragma unroll
  for (int r = 0; r < 16; ++r) {
    int j = ty * 16 + r;
    out[(size_t)(j0 + j) * 512 + k0 + tx] = t[tx][j];
  }
}

// ---------------------------------------------------------------------------
// GEMM1: Zlin = gelu(Xb @ Wv), depth-4 pipelined.
// BM=64 BN=128 BK=32, 256 thr (4 waves, each 32x64 = 2x4 frags of 16x16).
// Per wave per stage: 3 gll16 instructions (1 A + 2 B) -> vmcnt counts 3/stage.
// Loop invariant at iter kk (after prologue stages 0,1,2):
//   pending stages = {kk?, kk+1, kk+2} -> wait vmcnt(6) makes buf[kk] ready.
//   stage(kk+3) is issued only AFTER barrier2 (all waves done reading the
//   buffer it overwrites, which was consumed at iter kk-1).
// ---------------------------------------------------------------------------
__global__ __launch_bounds__(256) void k_gemm1(
    const uint16_t* __restrict__ Xb,   // [8192][512] bf16
    const uint16_t* __restrict__ WT,   // [512][512] bf16, WT[col][k]
    uint16_t* __restrict__ Zlin) {     // [8192][512] bf16, LINEAR
  __shared__ __align__(16) uint16_t As[4][4][64][8];    // 16 KB
  __shared__ __align__(16) uint16_t Bs[4][4][128][8];   // 32 KB

  const int tid = threadIdx.x;
  const int lane = tid & 63;
  const int wid = tid >> 6;
  const int wm = wid >> 1;
  const int wn = wid & 1;
  const int tm = blockIdx.y * 64;
  const int tn = blockIdx.x * 128;

  f32x4 acc[2][4];
  const f32x4 zero = {0.f, 0.f, 0.f, 0.f};
#pragma unroll
  for (int i = 0; i < 2; ++i)
#pragma unroll
    for (int j = 0; j < 4; ++j) acc[i][j] = zero;

  auto stage = [&](int kk) {
    const int buf = kk & 3;
    gll16(Xb + (size_t)(tm + lane) * 512 + kk * 32 + wid * 8,
          &As[buf][wid][0][0]);
#pragma unroll
    for (int s = 0; s < 2; ++s) {
      int t = wid + 4 * s;
      int kc = t >> 1;
      int cb = (t & 1) * 64;
      gll16(WT + (size_t)(tn + cb + lane) * 512 + kk * 32 + kc * 8,
            &Bs[buf][kc][cb][0]);
    }
  };

  // Prologue: 3 stages in flight (9 vmcnt per wave).
  stage(0);
  stage(1);
  stage(2);

  const int lr = lane & 15;
  const int lk = lane >> 4;

  for (int kk = 0; kk < 16; ++kk) {
    const int cur = kk & 3;
    // Buffer kk ready once only stages kk+1,kk+2 (<=6 loads) remain in flight.
    asm volatile("s_waitcnt vmcnt(6)" ::: "memory");
    __builtin_amdgcn_sched_barrier(0);
    __builtin_amdgcn_s_barrier();          // all waves' buf[kk] loads landed
    __builtin_amdgcn_sched_barrier(0);

    bf16x8 a[2], b[4];
#pragma unroll
    for (int mi = 0; mi < 2; ++mi)
      a[mi] = *(const bf16x8*)&As[cur][lk][wm * 32 + mi * 16 + lr][0];
#pragma unroll
    for (int nj = 0; nj < 4; ++nj)
      b[nj] = *(const bf16x8*)&Bs[cur][lk][wn * 64 + nj * 16 + lr][0];
#pragma unroll
    for (int mi = 0; mi < 2; ++mi)
#pragma unroll
      for (int nj = 0; nj < 4; ++nj)
        acc[mi][nj] = __builtin_amdgcn_mfma_f32_16x16x32_bf16(
            a[mi], b[nj], acc[mi][nj], 0, 0, 0);

    // All this wave's LDS reads retired before anyone overwrites the buffer.
    asm volatile("s_waitcnt lgkmcnt(0)" ::: "memory");
    __builtin_amdgcn_sched_barrier(0);
    __builtin_amdgcn_s_barrier();          // all waves done reading old bufs
    __builtin_amdgcn_sched_barrier(0);
    if (kk + 3 < 16) stage(kk + 3);        // overwrites buf consumed at kk-1
  }

  // Epilogue: inline gelu + linear bf16 store.
#pragma unroll
  for (int mi = 0; mi < 2; ++mi)
#pragma unroll
    for (int nj = 0; nj < 4; ++nj)
#pragma unroll
      for (int r = 0; r < 4; ++r) {
        int m = tm + wm * 32 + mi * 16 + lk * 4 + r;
        int j = tn + wn * 64 + nj * 16 + lr;
        Zlin[(size_t)m * 512 + j] = f2bf(gelu(acc[mi][nj][r]));
      }
}

// ---------------------------------------------------------------------------
// GEMM2: Y = Z @ Wout + bias, fp32 out. Permutation folded into A-source
// addressing (unchanged from R6 — proven ~2.5 us).
// ---------------------------------------------------------------------------
__global__ __launch_bounds__(256) void k_gemm_bias(
    const uint16_t* __restrict__ Zlin, // [8192][512] bf16, linear V-gelu
    const uint16_t* __restrict__ WT,   // [512][512] bf16, WoT[col][k]
    const float* __restrict__ bias,    // [512]
    float* __restrict__ Y) {           // [8192][512] fp32
  __shared__ __align__(16) uint16_t As[2][4][64][8];
  __shared__ __align__(16) uint16_t Bs[2][4][128][8];

  const int tid = threadIdx.x;
  const int lane = tid & 63;
  const int wid = tid >> 6;
  const int wm = wid >> 1;
  const int wn = wid & 1;
  const int tm = blockIdx.y * 64;
  const int tn = blockIdx.x * 128;

  f32x4 acc[2][4];
  const f32x4 zero = {0.f, 0.f, 0.f, 0.f};
#pragma unroll
  for (int i = 0; i < 2; ++i)
#pragma unroll
    for (int j = 0; j < 4; ++j) acc[i][j] = zero;

  const int m2 = tm + lane;
  const int bi = m2 >> 12;
  const int pp = (m2 >> 8) & 15;
  const int ni = m2 & 255;
  const int mbase = bi * 4096 + (pp >> 3) * 256 + ni;  // + q*512 rows
  const int jbase = (pp & 7) * 64;

  auto stage = [&](int kk, int buf) {
    int k2 = kk * 32 + wid * 8;
    int q = k2 >> 6;
    int di = k2 & 63;
    gll16(Zlin + (size_t)(mbase + q * 512) * 512 + jbase + di,
          &As[buf][wid][0][0]);
#pragma unroll
    for (int s = 0; s < 2; ++s) {
      int t = wid + 4 * s;
      int kc = t >> 1;
      int cb = (t & 1) * 64;
      gll16(WT + (size_t)(tn + cb + lane) * 512 + kk * 32 + kc * 8,
            &Bs[buf][kc][cb][0]);
    }
  };

  stage(0, 0);
  __syncthreads();

  const int lr = lane & 15;
  const int lk = lane >> 4;

#pragma unroll 2
  for (int kk = 0; kk < 16; ++kk) {
    const int cur = kk & 1;
    if (kk + 1 < 16) stage(kk + 1, cur ^ 1);
    bf16x8 a[2], b[4];
#pragma unroll
    for (int mi = 0; mi < 2; ++mi)
      a[mi] = *(const bf16x8*)&As[cur][lk][wm * 32 + mi * 16 + lr][0];
#pragma unroll
    for (int nj = 0; nj < 4; ++nj)
      b[nj] = *(const bf16x8*)&Bs[cur][lk][wn * 64 + nj * 16 + lr][0];
#pragma unroll
    for (int mi = 0; mi < 2; ++mi)
#pragma unroll
      for (int nj = 0; nj < 4; ++nj)
        acc[mi][nj] = __builtin_amdgcn_mfma_f32_16x16x32_bf16(
            a[mi], b[nj], acc[mi][nj], 0, 0, 0);
    __syncthreads();
  }

#pragma unroll
  for (int mi = 0; mi < 2; ++mi)
#pragma unroll
    for (int nj = 0; nj < 4; ++nj) {
      int j = tn + wn * 64 + nj * 16 + lr;
      float bj = bias[j];
#pragma unroll
      for (int r = 0; r < 4; ++r) {
        int m = tm + wm * 32 + mi * 16 + lk * 4 + r;
        Y[(size_t)m * 512 + j] = acc[mi][nj][r] + bj;
      }
    }
}

// ---------------------------------------------------------------------------
extern "C" void kernel_launch(void* const* d_in, const int* in_sizes, int n_in,
                              void* d_out, int out_size, void* d_ws, size_t ws_size,
                              hipStream_t stream) {
  const float* x    = (const float*)d_in[0];
  // d_in[1] = grad : provably unused by the reference's dataflow.
  const float* Wqkv = (const float*)d_in[2];   // [512][1536]
  const float* Wout = (const float*)d_in[3];   // [512][512]
  const float* bout = (const float*)d_in[4];   // [512]
  float* Y = (float*)d_out;

  uint16_t* WvT = (uint16_t*)d_ws;             // 512*512 bf16 (0.5 MB)
  uint16_t* WoT = WvT + 512 * 512;             // 0.5 MB
  uint16_t* Z   = WoT + 512 * 512;             // 8192*512 bf16 (8 MB)
  uint16_t* Xb  = Z + 8192 * 512;              // 8192*512 bf16 (8 MB)

  dim3 tb(256);
  k_cvtx<<<dim3(2048), tb, 0, stream>>>(x, Xb);
  k_prep<<<dim3(8, 8, 2), tb, 0, stream>>>(Wqkv, Wout, WvT, WoT);
  k_gemm1<<<dim3(4, 128), tb, 0, stream>>>(Xb, WvT, Z);
  k_gemm_bias<<<dim3(4, 128), tb, 0, stream>>>(Z, WoT, bout, Y);
}